// Round 1
// baseline (49.141 us; speedup 1.0000x reference)
//
#include <hip/hip_runtime.h>

// Problem: d2 (B=32, L=2048, K=512) fp32.
// z_t = clip(0.9*z_{t-1} + 0.1*d2_t, 0, 5), z_{-1}=0, scan over t (axis 1).
//
// Strategy: split L into NC chunks; each thread owns one (b, chunk, k) and
// runs the scan over its chunk, warming up from z=0 starting W steps early.
// Error of truncated look-back: <= 0.9^W * z_max_actual (~1.0) = 1.2e-3 for
// W=64, well under the harness threshold (1.63e-2). Chunk 0 is exact.

constexpr int B  = 32;
constexpr int L  = 2048;
constexpr int K  = 512;
constexpr int NC = 8;            // chunks along L
constexpr int C  = L / NC;       // 256
constexpr int W  = 64;           // warmup steps (0.9^64 ~ 1.2e-3)

__global__ __launch_bounds__(256)
void ema_chunk_kernel(const float* __restrict__ d2, float* __restrict__ out) {
    const float lam = 0.9f, om = 0.1f, zmax = 5.0f;

    int tid = blockIdx.x * blockDim.x + threadIdx.x;   // over B*NC*K = 131072
    int k   = tid & (K - 1);
    int bc  = tid >> 9;          // / K
    int c   = bc & (NC - 1);
    int b   = bc >> 3;           // / NC

    const float* in = d2  + (size_t)b * L * K + k;
    float*       o  = out + (size_t)b * L * K + k;

    int t0 = c * C;
    int tw = t0 - W;
    if (tw < 0) tw = 0;

    float z = 0.0f;

    // warmup (no stores)
    #pragma unroll 8
    for (int t = tw; t < t0; ++t) {
        float d = in[(size_t)t * K];
        z = fminf(fmaxf(lam * z + om * d, 0.0f), zmax);
    }

    // main chunk
    #pragma unroll 8
    for (int t = t0; t < t0 + C; ++t) {
        float d = in[(size_t)t * K];
        z = fminf(fmaxf(lam * z + om * d, 0.0f), zmax);
        o[(size_t)t * K] = z;
    }
}

extern "C" void kernel_launch(void* const* d_in, const int* in_sizes, int n_in,
                              void* d_out, int out_size, void* d_ws, size_t ws_size,
                              hipStream_t stream) {
    const float* d2 = (const float*)d_in[0];
    float* out = (float*)d_out;

    int total = B * NC * K;                 // 131072 threads
    int block = 256;
    int grid  = total / block;              // 512 blocks
    ema_chunk_kernel<<<grid, block, 0, stream>>>(d2, out);
}